// Round 3
// baseline (1456.592 us; speedup 1.0000x reference)
//
#include <hip/hip_runtime.h>

// NystromAttention on MI355X (gfx950). fp16 MFMA (f32 accum) everywhere.
// GEMM convention: C[M,N] = A[M,K] @ Bt[N,K]^T, A/Bt fp16 row-major.

typedef _Float16 h16;
typedef __attribute__((ext_vector_type(4))) float    f32x4;
typedef __attribute__((ext_vector_type(8))) _Float16 h16x8;
typedef __attribute__((ext_vector_type(4))) _Float16 h16x4;

struct GArgs {
  const h16* A; int lda; long abatch;
  const h16* B; int ldb; long bbatch;   // B^T stored [N][ldb]
  int M, N, K;
  float alpha, beta;
  const h16* auxh; long auxhb;          // val = alpha*P + beta*auxh
  float* of32; long ofb;
  h16* oh;  long ohb;
  h16* oht; long ohtb;                  // transposed out [N][M]
  const float* bias;
  h16* q; h16* k; h16* vt;              // QKV mode only
};

template<int BM,int BN,int WM,int WN,bool QKV>
__launch_bounds__((BM/WM)*(BN/WN)*64)
__global__ void gemm_k(GArgs g)
{
  constexpr int NWN = BN/WN;
  constexpr int FM = WM/16, FN = WN/16;
  constexpr int TH = (BM/WM)*NWN*64;
  constexpr int LA = (BM*32)/(TH*8);
  constexpr int LB = (BN*32)/(TH*8);
  __shared__ __align__(16) h16 As[BM][40];
  __shared__ __align__(16) h16 Bs[BN][40];
  const int tid = threadIdx.x;
  const int wv = tid >> 6, lane = tid & 63;
  const int wm = wv / NWN, wn = wv % NWN;
  const int l16 = lane & 15, lk = lane >> 4;
  const long bm = (long)blockIdx.y * BM;
  const long bn = (long)blockIdx.x * BN;
  const int bat = blockIdx.z;
  const h16* Ab = g.A + (long)bat * g.abatch;
  const h16* Bb = g.B + (long)bat * g.bbatch;

  f32x4 acc[FM][FN] = {};

  for (int k0 = 0; k0 < g.K; k0 += 32) {
    __syncthreads();
    #pragma unroll
    for (int i = 0; i < LA; ++i) {
      const int e = (i*TH + tid) * 8;
      const int r = e >> 5, c = e & 31;
      *(f32x4*)(&As[r][c]) = *(const f32x4*)(Ab + (bm + r)*(long)g.lda + k0 + c);
    }
    #pragma unroll
    for (int i = 0; i < LB; ++i) {
      const int e = (i*TH + tid) * 8;
      const int r = e >> 5, c = e & 31;
      *(f32x4*)(&Bs[r][c]) = *(const f32x4*)(Bb + (bn + r)*(long)g.ldb + k0 + c);
    }
    __syncthreads();
    h16x8 af[FM], bf[FN];
    #pragma unroll
    for (int m = 0; m < FM; ++m)
      af[m] = *(const h16x8*)(&As[wm*WM + m*16 + l16][lk*8]);
    #pragma unroll
    for (int n = 0; n < FN; ++n)
      bf[n] = *(const h16x8*)(&Bs[wn*WN + n*16 + l16][lk*8]);
    #pragma unroll
    for (int m = 0; m < FM; ++m)
      #pragma unroll
      for (int n = 0; n < FN; ++n)
        acc[m][n] = __builtin_amdgcn_mfma_f32_16x16x32_f16(af[m], bf[n], acc[m][n], 0, 0, 0);
  }

  // D layout: col = lane&15, row = (lane>>4)*4 + reg
  const long r0 = bm + wm*WM;
  const long c0 = bn + wn*WN;
  #pragma unroll
  for (int m = 0; m < FM; ++m) {
    #pragma unroll
    for (int n = 0; n < FN; ++n) {
      #pragma unroll
      for (int rr = 0; rr < 4; ++rr) {
        const long row = r0 + m*16 + lk*4 + rr;
        const long col = c0 + n*16 + l16;
        float v = acc[m][n][rr];
        if (QKV) {
          const int b   = (int)(row >> 12);
          const int nn  = (int)(row & 4095);
          const int whc = (int)(col >> 10);
          const int rem = (int)(col & 1023);
          const int hh = rem >> 6, dd = rem & 63;
          const long bh = (long)b*16 + hh;
          if (whc == 0)      g.q [(bh*4096 + nn)*64 + dd] = (h16)(v * 0.125f);
          else if (whc == 1) g.k [(bh*4096 + nn)*64 + dd] = (h16)v;
          else               g.vt[(bh*64 + dd)*4096 + nn] = (h16)v;
        } else {
          v *= g.alpha;
          if (g.auxh) v += g.beta * (float)g.auxh[(long)bat*g.auxhb + row*(long)g.N + col];
          if (g.bias) v += g.bias[col];
          if (g.of32) g.of32[(long)bat*g.ofb  + row*(long)g.N + col] = v;
          if (g.oh)   g.oh  [(long)bat*g.ohb  + row*(long)g.N + col] = (h16)v;
          if (g.oht)  g.oht [(long)bat*g.ohtb + col*(long)g.M + row] = (h16)v;
        }
      }
    }
  }
}

// row softmax over 256 cols, f32 in (in-place ok), writes f16 + f32
__launch_bounds__(256)
__global__ void sm256_k(const float* __restrict__ inp, h16* __restrict__ oh,
                        float* __restrict__ o32)
{
  const int wid = threadIdx.x >> 6, lane = threadIdx.x & 63;
  const long row = (long)blockIdx.x*4 + wid;
  float v[4];
  *(f32x4*)v = *(const f32x4*)(inp + row*256 + lane*4);
  float mx = fmaxf(fmaxf(v[0],v[1]), fmaxf(v[2],v[3]));
  for (int o = 32; o; o >>= 1) mx = fmaxf(mx, __shfl_xor(mx, o, 64));
  float sm = 0.f;
  #pragma unroll
  for (int j = 0; j < 4; ++j) { v[j] = __expf(v[j]-mx); sm += v[j]; }
  for (int o = 32; o; o >>= 1) sm += __shfl_xor(sm, o, 64);
  const float inv = 1.0f/sm;
  h16x4 t; f32x4 t2;
  #pragma unroll
  for (int u = 0; u < 4; ++u) { t[u] = (h16)(v[u]*inv); t2[u] = v[u]*inv; }
  *(h16x4*)(oh + row*256 + lane*4) = t;
  *(f32x4*)(o32 + row*256 + lane*4) = t2;
}

// landmark mean over groups of 16 tokens: [bh,4096,64] -> [bh,256,64]
__global__ void landmark_k(const h16* __restrict__ in, h16* __restrict__ out)
{
  const long i = (long)blockIdx.x*256 + threadIdx.x;
  const int d = (int)(i & 63);
  const long m = (i >> 6) & 255;
  const long bh = i >> 14;
  const h16* p = in + (bh*4096 + m*16)*64 + d;
  float s = 0.f;
  #pragma unroll
  for (int j = 0; j < 16; ++j) s += (float)p[j*64];
  out[i] = (h16)(s * 0.0625f);
}

__global__ void a_scale_k(const float* __restrict__ a, float* scal)
{
  const int bh = blockIdx.x, t = threadIdx.x;
  const float* p = a + (long)bh*65536;
  float cs = 0.f, rs = 0.f;
  for (int i = 0; i < 256; ++i) cs += p[(long)i*256 + t];
  for (int j = 0; j < 256; ++j) rs += p[(long)t*256 + j];
  for (int o = 32; o; o >>= 1) { cs = fmaxf(cs, __shfl_xor(cs,o,64)); rs = fmaxf(rs, __shfl_xor(rs,o,64)); }
  __shared__ float red[8];
  if ((t & 63) == 0) { red[t>>6] = cs; red[4+(t>>6)] = rs; }
  __syncthreads();
  if (t == 0) {
    float c = fmaxf(fmaxf(red[0],red[1]),fmaxf(red[2],red[3]));
    float r = fmaxf(fmaxf(red[4],red[5]),fmaxf(red[6],red[7]));
    atomicMax((int*)scal,     __float_as_int(c));
    atomicMax((int*)(scal+1), __float_as_int(r));
  }
}

__global__ void init_k(float* s) { if (threadIdx.x < 2) s[threadIdx.x] = 0.f; }

// z0 = a^T / (maxc*maxr): zh = z0 (f16), zt = z0^T = a*inv (f16)
__global__ void z0_k(const float* __restrict__ a, const float* __restrict__ scal,
                     h16* __restrict__ zh, h16* __restrict__ zt)
{
  __shared__ float t[64][65];
  const int bh = blockIdx.y;
  const int i0 = (blockIdx.x >> 2)*64, j0 = (blockIdx.x & 3)*64;
  const float inv = 1.0f/(scal[0]*scal[1]);
  const long base = (long)bh*65536;
  const int tt = threadIdx.x;
  for (int it = 0; it < 16; ++it) {
    const int e = it*256 + tt;
    const int r = e >> 6, c = e & 63;
    const float v = a[base + (long)(j0+r)*256 + i0 + c];
    t[r][c] = v;
    zt[base + (long)(j0+r)*256 + i0 + c] = (h16)(v*inv);
  }
  __syncthreads();
  for (int it = 0; it < 16; ++it) {
    const int e = it*256 + tt;
    const int r = e >> 6, c = e & 63;
    zh[base + (long)(i0+r)*256 + j0 + c] = (h16)(t[c][r]*inv);
  }
}

// flash: av = softmax(q_l @ K^T) @ V  -> avt [bh][64][256]
__launch_bounds__(256)
__global__ void flash_av_k(const h16* __restrict__ ql, const h16* __restrict__ kh,
                           const h16* __restrict__ vt, h16* __restrict__ avt)
{
  __shared__ __align__(16) h16 Ks[64][72];
  __shared__ __align__(16) h16 Vs[64][72];
  __shared__ __align__(16) h16 Ps[4][16][72];
  const int tid = threadIdx.x;
  const int wv = tid>>6, lane = tid&63, l16 = lane&15, lk = lane>>4;
  const int bx = blockIdx.x;
  const int bh   = (bx&7)*8 + ((bx>>3)&7);   // 4 m-splits of one bh share an XCD
  const int mblk = bx>>6;
  const int row0 = mblk*64 + wv*16;
  h16x8 af[2];
  {
    const h16* qp = ql + (long)bh*16384 + (long)(row0 + l16)*64;
    af[0] = *(const h16x8*)(qp + lk*8);
    af[1] = *(const h16x8*)(qp + 32 + lk*8);
  }
  const int sr = tid>>3, sc = (tid&7)*8;
  const h16* kbase = kh + (long)bh*262144;
  const h16* vbase = vt + (long)bh*262144;
  float m_st[4], l_st[4];
  f32x4 acc[4] = {};
  #pragma unroll
  for (int r = 0; r < 4; ++r) { m_st[r] = -1e30f; l_st[r] = 0.f; }

  for (int jt = 0; jt < 64; ++jt) {
    __syncthreads();
    *(f32x4*)(&Ks[sr][sc])    = *(const f32x4*)(kbase + (long)(jt*64+sr)*64 + sc);
    *(f32x4*)(&Ks[sr+32][sc]) = *(const f32x4*)(kbase + (long)(jt*64+sr+32)*64 + sc);
    *(f32x4*)(&Vs[sr][sc])    = *(const f32x4*)(vbase + (long)sr*4096 + jt*64 + sc);
    *(f32x4*)(&Vs[sr+32][sc]) = *(const f32x4*)(vbase + (long)(sr+32)*4096 + jt*64 + sc);
    __syncthreads();
    f32x4 sacc[4];
    #pragma unroll
    for (int n = 0; n < 4; ++n) {
      h16x8 b0 = *(const h16x8*)(&Ks[n*16+l16][lk*8]);
      h16x8 b1 = *(const h16x8*)(&Ks[n*16+l16][32+lk*8]);
      f32x4 s = {};
      s = __builtin_amdgcn_mfma_f32_16x16x32_f16(af[0], b0, s, 0,0,0);
      s = __builtin_amdgcn_mfma_f32_16x16x32_f16(af[1], b1, s, 0,0,0);
      sacc[n] = s;
    }
    float pexp[4][4];
    #pragma unroll
    for (int rr = 0; rr < 4; ++rr) {
      float tm = fmaxf(fmaxf(sacc[0][rr],sacc[1][rr]), fmaxf(sacc[2][rr],sacc[3][rr]));
      #pragma unroll
      for (int o = 1; o < 16; o <<= 1) tm = fmaxf(tm, __shfl_xor(tm, o, 64));
      const float mn = fmaxf(m_st[rr], tm);
      const float scl = __expf(m_st[rr] - mn);
      m_st[rr] = mn;
      float ts = 0.f;
      #pragma unroll
      for (int n = 0; n < 4; ++n) { float e = __expf(sacc[n][rr]-mn); pexp[n][rr] = e; ts += e; }
      #pragma unroll
      for (int o = 1; o < 16; o <<= 1) ts += __shfl_xor(ts, o, 64);
      l_st[rr] = l_st[rr]*scl + ts;
      #pragma unroll
      for (int n = 0; n < 4; ++n) acc[n][rr] *= scl;
    }
    #pragma unroll
    for (int n = 0; n < 4; ++n)
      #pragma unroll
      for (int rr = 0; rr < 4; ++rr)
        Ps[wv][lk*4+rr][n*16+l16] = (h16)pexp[n][rr];
    #pragma unroll
    for (int kk = 0; kk < 2; ++kk) {
      h16x8 pa = *(const h16x8*)(&Ps[wv][l16][kk*32+lk*8]);
      #pragma unroll
      for (int n = 0; n < 4; ++n) {
        h16x8 vf = *(const h16x8*)(&Vs[n*16+l16][kk*32+lk*8]);
        acc[n] = __builtin_amdgcn_mfma_f32_16x16x32_f16(pa, vf, acc[n], 0,0,0);
      }
    }
  }
  #pragma unroll
  for (int n = 0; n < 4; ++n)
    #pragma unroll
    for (int rr = 0; rr < 4; ++rr) {
      const int d = n*16+l16, rw = row0 + lk*4 + rr;
      avt[(long)bh*16384 + (long)d*256 + rw] = (h16)(acc[n][rr] / l_st[rr]);
    }
}

// fused: out = softmax(q @ k_l^T) @ zav  -> f32 [bh][4096][64]
__launch_bounds__(256)
__global__ void flash_out_k(const h16* __restrict__ qh, const h16* __restrict__ kl,
                            const h16* __restrict__ zavt, float* __restrict__ outp)
{
  __shared__ __align__(16) h16 Ps[4][16][264];
  const int tid = threadIdx.x;
  const int wv = tid>>6, lane = tid&63, l16 = lane&15, lk = lane>>4;
  const int bh = blockIdx.y;
  const int row0 = blockIdx.x*64 + wv*16;
  h16x8 af[2];
  {
    const h16* qp = qh + (long)bh*262144 + (long)(row0+l16)*64;
    af[0] = *(const h16x8*)(qp + lk*8);
    af[1] = *(const h16x8*)(qp + 32 + lk*8);
  }
  const h16* kp = kl + (long)bh*16384;
  f32x4 sacc[16];
  #pragma unroll
  for (int n = 0; n < 16; ++n) {
    h16x8 b0 = *(const h16x8*)(kp + (long)(n*16+l16)*64 + lk*8);
    h16x8 b1 = *(const h16x8*)(kp + (long)(n*16+l16)*64 + 32 + lk*8);
    f32x4 s = {};
    s = __builtin_amdgcn_mfma_f32_16x16x32_f16(af[0], b0, s, 0,0,0);
    s = __builtin_amdgcn_mfma_f32_16x16x32_f16(af[1], b1, s, 0,0,0);
    sacc[n] = s;
  }
  float l_st[4];
  #pragma unroll
  for (int rr = 0; rr < 4; ++rr) {
    float tm = sacc[0][rr];
    #pragma unroll
    for (int n = 1; n < 16; ++n) tm = fmaxf(tm, sacc[n][rr]);
    #pragma unroll
    for (int o = 1; o < 16; o <<= 1) tm = fmaxf(tm, __shfl_xor(tm, o, 64));
    float ts = 0.f;
    #pragma unroll
    for (int n = 0; n < 16; ++n) {
      float e = __expf(sacc[n][rr]-tm);
      ts += e;
      Ps[wv][lk*4+rr][n*16+l16] = (h16)e;
    }
    #pragma unroll
    for (int o = 1; o < 16; o <<= 1) ts += __shfl_xor(ts, o, 64);
    l_st[rr] = ts;
  }
  const h16* zp = zavt + (long)bh*16384;
  f32x4 acc[4] = {};
  #pragma unroll
  for (int kk = 0; kk < 8; ++kk) {
    h16x8 pa = *(const h16x8*)(&Ps[wv][l16][kk*32+lk*8]);
    #pragma unroll
    for (int n = 0; n < 4; ++n) {
      h16x8 vf = *(const h16x8*)(zp + (long)(n*16+l16)*256 + kk*32 + lk*8);
      acc[n] = __builtin_amdgcn_mfma_f32_16x16x32_f16(pa, vf, acc[n], 0,0,0);
    }
  }
  #pragma unroll
  for (int n = 0; n < 4; ++n)
    #pragma unroll
    for (int rr = 0; rr < 4; ++rr)
      outp[(long)bh*262144 + (long)(row0+lk*4+rr)*64 + n*16+l16] = acc[n][rr]/l_st[rr];
}

// depthwise conv (K=13) + residual + [b,h,n,d]->[b,n,h*d] -> f16
__global__ void conv_res_k(const float* __restrict__ o, const float* __restrict__ wc,
                           h16* __restrict__ y)
{
  const long i = (long)blockIdx.x*256 + threadIdx.x;
  const int d  = (int)(i & 63);
  const int nn = (int)((i >> 6) & 4095);
  const long bh = i >> 18;
  const int h = (int)(bh & 15);
  const long b = bh >> 4;
  const float* base = o + bh*262144 + d;
  float acc = base[(long)nn*64];
  #pragma unroll
  for (int t = 0; t < 13; ++t) {
    const int n2 = nn + t - 6;
    if (0 <= n2 && n2 < 4096) acc += wc[h*13 + t] * base[(long)n2*64];
  }
  y[((b*4096 + nn)*16 + h)*64 + d] = (h16)acc;
}

__global__ void cvt_k(const float* __restrict__ x, h16* __restrict__ o)
{
  const long i = ((long)blockIdx.x*256 + threadIdx.x)*4;
  f32x4 v = *(const f32x4*)(x + i);
  h16x4 t;
  #pragma unroll
  for (int u = 0; u < 4; ++u) t[u] = (h16)v[u];
  *(h16x4*)(o + i) = t;
}

__global__ void tcvt_k(const float* __restrict__ in, h16* __restrict__ out, int R, int C)
{
  __shared__ h16 t[64][74];
  const int r0 = blockIdx.y*64, c0 = blockIdx.x*64;
  const int tt = threadIdx.x;
  for (int it = 0; it < 16; ++it) {
    const int e = it*256 + tt;
    const int r = e >> 6, c = e & 63;
    t[r][c] = (h16)in[(long)(r0+r)*C + c0 + c];
  }
  __syncthreads();
  for (int it = 0; it < 16; ++it) {
    const int e = it*256 + tt;
    const int r = e >> 6, c = e & 63;
    out[(long)(c0+r)*R + r0 + c] = t[c][r];
  }
}

static inline void g_gen(hipStream_t st, bool wide, int batches,
  const h16* A, int lda, long ab, const h16* B, int ldb, long bb,
  int M, int N, int K, float alpha, float beta, const h16* auxh, long auxhb,
  float* of32, long ofb, h16* oh, long ohb, h16* oht, long ohtb, const float* bias)
{
  GArgs g{A,lda,ab,B,ldb,bb,M,N,K,alpha,beta,auxh,auxhb,of32,ofb,oh,ohb,oht,ohtb,bias,
          nullptr,nullptr,nullptr};
  if (wide) { dim3 gr(N/128, M/128, batches); gemm_k<128,128,64,64,false><<<gr,256,0,st>>>(g); }
  else      { dim3 gr(N/64,  M/128, batches); gemm_k<128,64, 32,64,false><<<gr,256,0,st>>>(g); }
}

extern "C" void kernel_launch(void* const* d_in, const int* in_sizes, int n_in,
                              void* d_out, int out_size, void* d_ws, size_t ws_size,
                              hipStream_t stream)
{
  const float* x      = (const float*)d_in[0];
  const float* w_qkv  = (const float*)d_in[1];
  const float* w_conv = (const float*)d_in[2];
  const float* w_fc   = (const float*)d_in[3];
  const float* b_fc   = (const float*)d_in[4];
  float* out = (float*)d_out;
  char* ws = (char*)d_ws;

  // workspace layout, total ~243 MB
  h16*   xh    = (h16*)(ws + 0L);          // 32 MB (later yh)
  h16*   wqkvT = (h16*)(ws + 33554432L);   // 6 MB
  h16*   wfcT  = (h16*)(ws + 39845888L);   // 2 MB
  h16*   qh    = (h16*)(ws + 41943040L);   // 32 MB
  h16*   kh    = (h16*)(ws + 75497472L);   // 32 MB
  h16*   vt    = (h16*)(ws + 109051904L);  // 32 MB
  h16*   ql    = (h16*)(ws + 142606336L);  // 2 MB
  h16*   kl    = (h16*)(ws + 144703488L);  // 2 MB
  float* af32  = (float*)(ws + 146800640L);// 16 MB
  h16*   ah    = (h16*)(ws + 163577856L);  // 8 MB
  h16*   zh0   = (h16*)(ws + 171966464L);  // 8 MB
  h16*   zt0   = (h16*)(ws + 180355072L);  // 8 MB
  h16*   zh1   = (h16*)(ws + 188743680L);  // 8 MB
  h16*   zt1   = (h16*)(ws + 197132288L);  // 8 MB
  h16*   azh   = (h16*)(ws + 205520896L);  // 8 MB
  h16*   azt   = (h16*)(ws + 213909504L);  // 8 MB
  h16*   w1t   = (h16*)(ws + 222298112L);  // 8 MB
  h16*   w2t   = (h16*)(ws + 230686720L);  // 8 MB
  h16*   avt   = (h16*)(ws + 239075328L);  // 2 MB
  h16*   zavt  = (h16*)(ws + 241172480L);  // 2 MB
  float* scal  = (float*)(ws + 243269632L);
  h16*   zh[2] = {zh0, zh1};
  h16*   zt[2] = {zt0, zt1};
  h16*   yh    = xh;
  float* attn_out = out;                   // d_out as scratch (overwritten by final GEMM)

  cvt_k<<<16384, 256, 0, stream>>>(x, xh);
  { dim3 gr(48, 16); tcvt_k<<<gr, 256, 0, stream>>>(w_qkv, wqkvT, 1024, 3072); }
  { dim3 gr(16, 16); tcvt_k<<<gr, 256, 0, stream>>>(w_fc, wfcT, 1024, 1024); }
  init_k<<<1, 64, 0, stream>>>(scal);

  // qkv = x @ w_qkv -> q(scaled),k [bh,n,d]; v transposed [bh,d,n]
  {
    GArgs g{xh,1024,0, wqkvT,1024,0, 16384,3072,1024, 1.f,0.f,
            nullptr,0, nullptr,0, nullptr,0, nullptr,0, nullptr, qh, kh, vt};
    dim3 gr(24, 128, 1);
    gemm_k<128,128,64,64,true><<<gr, 256, 0, stream>>>(g);
  }

  landmark_k<<<4096, 256, 0, stream>>>(qh, ql);
  landmark_k<<<4096, 256, 0, stream>>>(kh, kl);

  // sim2 = q_l @ k_l^T (f32) -> softmax in-place (f32 + f16)
  g_gen(stream, true, 64, ql,64,16384, kl,64,16384, 256,256,64,
        1.f,0.f, nullptr,0, af32,65536, nullptr,0, nullptr,0, nullptr);
  sm256_k<<<4096, 256, 0, stream>>>(af32, ah, af32);

  a_scale_k<<<64, 256, 0, stream>>>(af32, scal);
  { dim3 gr(16, 64); z0_k<<<gr, 256, 0, stream>>>(af32, scal, zh[0], zt[0]); }

  // Moore-Penrose, 6 iters: az=a@z; w1=7az-az@az; w2=15az-az@w1; z'=3.25z-0.25 z@w2
  int cur = 0;
  for (int it = 0; it < 6; ++it) {
    g_gen(stream, true, 64, ah,256,65536, zt[cur],256,65536, 256,256,256,
          1.f,0.f, nullptr,0, nullptr,0, azh,65536, azt,65536, nullptr);
    g_gen(stream, true, 64, azh,256,65536, azt,256,65536, 256,256,256,
          -1.f,7.f, azh,65536, nullptr,0, nullptr,0, w1t,65536, nullptr);
    g_gen(stream, true, 64, azh,256,65536, w1t,256,65536, 256,256,256,
          -1.f,15.f, azh,65536, nullptr,0, nullptr,0, w2t,65536, nullptr);
    const int nxt = cur ^ 1;
    g_gen(stream, true, 64, zh[cur],256,65536, w2t,256,65536, 256,256,256,
          -0.25f,3.25f, zh[cur],65536, nullptr,0, zh[nxt],65536, zt[nxt],65536, nullptr);
    cur = nxt;
  }

  // av = softmax(q_l K^T) V  (flash) -> avt [bh,64,256]
  flash_av_k<<<256, 256, 0, stream>>>(ql, kh, vt, avt);

  // zav = z @ av -> zavt [bh,64,256]
  g_gen(stream, false, 64, zh[cur],256,65536, avt,256,16384, 256,64,256,
        1.f,0.f, nullptr,0, nullptr,0, nullptr,0, zavt,16384, nullptr);

  // attn_out = softmax(q k_l^T) @ zav -> f32 [bh,4096,64] (in d_out)
  { dim3 gr(64, 64); flash_out_k<<<gr, 256, 0, stream>>>(qh, kl, zavt, attn_out); }

  // conv residual + reshape -> yh (f16)
  conv_res_k<<<65536, 256, 0, stream>>>(attn_out, w_conv, yh);

  // out = y @ w_fc + b_fc
  g_gen(stream, true, 1, yh,1024,0, wfcT,1024,0, 16384,1024,1024,
        1.f,0.f, nullptr,0, out,0, nullptr,0, nullptr,0, b_fc);

  (void)in_sizes; (void)n_in; (void)out_size; (void)ws_size;
}